// Round 6
// baseline (223.817 us; speedup 1.0000x reference)
//
#include <hip/hip_runtime.h>

typedef unsigned short u16;
typedef unsigned int u32;
typedef __attribute__((ext_vector_type(4))) float f32x4;
typedef __attribute__((ext_vector_type(8))) __bf16 bf16x8;
typedef __attribute__((ext_vector_type(4))) u16 u16x4;
typedef __attribute__((ext_vector_type(2))) u32 u32x2;

// ---------- helpers ----------

__device__ __forceinline__ u16 f2bf(float f) {
  union { float f; unsigned u; } v; v.f = f;
  unsigned r = v.u + 0x7fffu + ((v.u >> 16) & 1u);
  return (u16)(r >> 16);
}

// pack two floats to bf16x2 (round-half-up) via v_perm
__device__ __forceinline__ u32 pack_bf2(float a, float b) {
  union { float f; unsigned u; } x, y;
  x.f = a; y.f = b;
#if __has_builtin(__builtin_amdgcn_perm)
  return __builtin_amdgcn_perm(y.u + 0x8000u, x.u + 0x8000u, 0x07060302u);
#else
  return (u32)((x.u + 0x8000u) >> 16) | ((y.u + 0x8000u) & 0xffff0000u);
#endif
}

__device__ __forceinline__ void stage16(const void* g, void* l) {
#if __has_builtin(__builtin_amdgcn_global_load_lds)
  __builtin_amdgcn_global_load_lds((const __attribute__((address_space(1))) void*)g,
                                   (__attribute__((address_space(3))) void*)l, 16, 0, 0);
#else
  *(f32x4*)l = *(const f32x4*)g;
#endif
}

__device__ __forceinline__ f32x4 mfma16(bf16x8 a, bf16x8 b, f32x4 c) {
  return __builtin_amdgcn_mfma_f32_16x16x32_bf16(a, b, c, 0, 0, 0);
}

__device__ __forceinline__ float fexp2(float x) {
#if __has_builtin(__builtin_amdgcn_exp2f)
  return __builtin_amdgcn_exp2f(x);
#else
  return exp2f(x);
#endif
}

// rope channel select: sections [16,24,24,16,24,24] -> channels 0,1,2,0,1,2
__device__ __forceinline__ int rope_ch(int d) {
  int dd = (d < 64) ? d : d - 64;
  return (dd < 16) ? 0 : (dd < 40 ? 1 : 2);
}

// ---------- kernels ----------

// Merged prep: one launch instead of two (independent, both memory-bound).
// bid < 4096:            weight transpose (mat = bid>>10)
// 4096 <= bid < 8192:    x fp32 -> bf16
// 8192 <= bid < 8448:    rope channel-select tables
__global__ void yuna_prep(const float* __restrict__ x, u16* __restrict__ xb,
                          const float* __restrict__ cosp, const float* __restrict__ sinp,
                          float* __restrict__ csel, float* __restrict__ ssel,
                          const float* __restrict__ Wq, const float* __restrict__ Wk,
                          const float* __restrict__ Wv, const float* __restrict__ Wo,
                          u16* __restrict__ Wb, u16* __restrict__ Wob) {
  __shared__ float tile[64][65];
  const int bid = blockIdx.x;
  if (bid < 4096) {
    // ---- fused weight transpose: out[n][k] = bf16(W[k][n]) ----
    const int mat = bid >> 10;
    const int rem = bid & 1023;
    const float* W;
    u16* out;
    int N;
    if (mat == 0)      { W = Wq; out = Wb;                          N = 2048; }
    else if (mat == 1) { W = Wk; out = Wb + (size_t)2048 * 2048;    N = 512; }
    else if (mat == 2) { W = Wv; out = Wb + (size_t)2560 * 2048;    N = 512; }
    else               { W = Wo; out = Wob;                         N = 2048; }
    int k0 = (rem & 31) << 6, n0 = (rem >> 5) << 6;
    if (n0 >= N) return;
    int tx = threadIdx.x & 63, ty = threadIdx.x >> 6;
#pragma unroll
    for (int j = 0; j < 64; j += 4)
      tile[ty + j][tx] = W[(size_t)(k0 + ty + j) * N + n0 + tx];
    __syncthreads();
#pragma unroll
    for (int j = 0; j < 64; j += 4)
      out[(size_t)(n0 + ty + j) * 2048 + k0 + tx] = f2bf(tile[tx][ty + j]);
  } else if (bid < 8192) {
    // ---- x fp32 -> bf16 ----
    int i = (bid - 4096) * 256 + threadIdx.x;
    f32x4 v = ((const f32x4*)x)[i];
    u16x4 o;
    o.x = f2bf(v.x); o.y = f2bf(v.y); o.z = f2bf(v.z); o.w = f2bf(v.w);
    ((u16x4*)xb)[i] = o;
  } else {
    // ---- rope tables csel/ssel[t][d] = cos/sin[ch(d)][t][d] ----
    int i = (bid - 8192) * 256 + threadIdx.x;  // 0..65535, 4 elems each
    int i4 = i * 4;
    int t = i4 >> 7, d = i4 & 127;
    f32x4 c, s;
#pragma unroll
    for (int j = 0; j < 4; ++j) {
      int ch = rope_ch(d + j);
      c[j] = cosp[(size_t)ch * 262144 + (size_t)t * 128 + d + j];
      s[j] = sinp[(size_t)ch * 262144 + (size_t)t * 128 + d + j];
    }
    ((f32x4*)csel)[i] = c;
    ((f32x4*)ssel)[i] = s;
  }
}

// Fused QKV GEMM + bias + rope + scatter.  R6: reverted to R4 geometry --
// 64x128 tile, grid (32,24) = 768 blocks = exactly 3/CU (R5's 128x128 at
// 1.5 blk/CU was concurrency-imbalanced and slower).
// A [2048][2048] bf16 (x), Bt [3072][2048] bf16 (W^T fused).
// Column mapping: wave w owns cols {w*16..+15} u {w*16+64..+79}: rope pair
// in-lane.  by<16 -> Q head, 16..19 -> K head, 20..23 -> V head.
__global__ __launch_bounds__(256, 3) void yuna_gemm_qkv(
    const u16* __restrict__ A, const u16* __restrict__ Bt,
    const float* __restrict__ bq, const float* __restrict__ bk, const float* __restrict__ bv,
    const float* __restrict__ csel, const float* __restrict__ ssel,
    u16* __restrict__ qb, u16* __restrict__ kb, u16* __restrict__ vtb,
    float* __restrict__ pk, float* __restrict__ pv) {
  const int K = 2048;
  __shared__ __align__(16) char smem[49152];  // As[2]:16K @0, Bs[2]:32K @16K
  const int tid = threadIdx.x;
  const int wave = tid >> 6, lane = tid & 63;
  const int lrow = lane & 15, lkg = lane >> 4;
  const int m0 = blockIdx.x * 64;
  const int by = blockIdx.y;
  const int n0 = by * 128;
  const int sw = lrow & 7;

  const int srow = tid >> 3;
  const int ssc = (tid & 7) ^ ((tid >> 3) & 7);
  const size_t abase = (size_t)(m0 + srow) * K + ssc * 8;
  const size_t bbase = (size_t)(n0 + srow) * K + ssc * 8;

  const f32x4 fzero = {0.f, 0.f, 0.f, 0.f};
  f32x4 acc[4][2];
#pragma unroll
  for (int mi = 0; mi < 4; ++mi) { acc[mi][0] = fzero; acc[mi][1] = fzero; }

  // prologue: stage k-tile 0 into buffer 0 (6 loads/thread)
#pragma unroll
  for (int it = 0; it < 2; ++it)
    stage16(A + abase + (size_t)it * 32 * K, smem + (tid + it * 256) * 16);
#pragma unroll
  for (int it = 0; it < 4; ++it)
    stage16(Bt + bbase + (size_t)it * 32 * K, smem + 16384 + (tid + it * 256) * 16);

  for (int k0 = 0, ki = 0; k0 < K; k0 += 64, ++ki) {
    const int cur = ki & 1;
    const char* Asb = smem + cur * 8192;
    const char* Bsb = smem + 16384 + cur * 16384;
    if (k0 + 64 < K) {
      char* Asn = smem + (cur ^ 1) * 8192;
      char* Bsn = smem + 16384 + (cur ^ 1) * 16384;
#pragma unroll
      for (int it = 0; it < 2; ++it)
        stage16(A + abase + (size_t)it * 32 * K + k0 + 64, Asn + (tid + it * 256) * 16);
#pragma unroll
      for (int it = 0; it < 4; ++it)
        stage16(Bt + bbase + (size_t)it * 32 * K + k0 + 64, Bsn + (tid + it * 256) * 16);
      asm volatile("s_waitcnt vmcnt(6)\n\ts_barrier" ::: "memory");
    } else {
      asm volatile("s_waitcnt vmcnt(0)\n\ts_barrier" ::: "memory");
    }
#pragma unroll
    for (int kk = 0; kk < 2; ++kk) {
      const int cof = ((kk * 4 + lkg) ^ sw) << 4;
      bf16x8 af[4], bfr[2];
#pragma unroll
      for (int mi = 0; mi < 4; ++mi)
        af[mi] = *(const bf16x8*)(Asb + (mi * 16 + lrow) * 128 + cof);
#pragma unroll
      for (int ni = 0; ni < 2; ++ni)
        bfr[ni] = *(const bf16x8*)(Bsb + (wave * 16 + ni * 64 + lrow) * 128 + cof);
#pragma unroll
      for (int mi = 0; mi < 4; ++mi)
#pragma unroll
        for (int ni = 0; ni < 2; ++ni)
          acc[mi][ni] = mfma16(af[mi], bfr[ni], acc[mi][ni]);
    }
    asm volatile("s_barrier" ::: "memory");
  }

  // ---- epilogue ----  acc[mi][ni][r]: t = m0+mi*16+lkg*4+r, d = wave*16+ni*64+lrow
  if (by >= 20) {
    // V: bias, write pv fp32 [kvh][t][d] + vtb bf16 [kvh][d][t] (4 t's packed)
    const int kvh = by - 20;
#pragma unroll
    for (int mi = 0; mi < 4; ++mi)
#pragma unroll
      for (int ni = 0; ni < 2; ++ni) {
        int d = wave * 16 + ni * 64 + lrow;
        float bb = bv[kvh * 128 + d];
        int mb = mi * 16 + lkg * 4;
        float v0 = acc[mi][ni][0] + bb, v1 = acc[mi][ni][1] + bb;
        float v2 = acc[mi][ni][2] + bb, v3 = acc[mi][ni][3] + bb;
        size_t pb = ((size_t)(kvh * 2048 + m0 + mb)) * 128 + d;
        pv[pb] = v0; pv[pb + 128] = v1; pv[pb + 256] = v2; pv[pb + 384] = v3;
        u16x4 w;
        w.x = f2bf(v0); w.y = f2bf(v1); w.z = f2bf(v2); w.w = f2bf(v3);
        *(u16x4*)(vtb + ((size_t)(kvh * 128 + d)) * 2048 + m0 + mb) = w;
      }
  } else {
    // Q/K: rope entirely in registers (acc[mi][0] = chan d, acc[mi][1] = chan d+64)
    const float QSCALE = 1.4426950408889634f * 0.08838834764831845f;
    const bool isQ = (by < 16);
    const int h = isQ ? by : (by - 16);
    const float* bias = isQ ? bq : bk;
    const int dlo = wave * 16 + lrow;
    const float blo = bias[h * 128 + dlo];
    const float bhi = bias[h * 128 + dlo + 64];
#pragma unroll
    for (int mi = 0; mi < 4; ++mi) {
      const int tb = m0 + mi * 16 + lkg * 4;
#pragma unroll
      for (int r = 0; r < 4; ++r) {
        const int t = tb + r;
        float a = acc[mi][0][r] + blo;
        float b = acc[mi][1][r] + bhi;
        size_t cb = (size_t)t * 128 + dlo;
        float cl = csel[cb], sl = ssel[cb];
        float ch = csel[cb + 64], sh = ssel[cb + 64];
        float lo = a * cl - b * sl;
        float hi = b * ch + a * sh;
        size_t o = (((size_t)(h * 2048 + t)) << 7) + dlo;
        if (isQ) {
          qb[o] = f2bf(lo * QSCALE);
          qb[o + 64] = f2bf(hi * QSCALE);
        } else {
          kb[o] = f2bf(lo);
          kb[o + 64] = f2bf(hi);
          pk[o] = lo; pk[o + 64] = hi;
        }
      }
    }
  }
}

// Output GEMM: C[2048][2048] fp32 = A(yat) @ Wob^T.  R6: reverted to R4
// geometry -- 64x128 tile, grid (32,16) = 512 = exactly 2/CU.
__global__ __launch_bounds__(256, 3) void yuna_gemm_out(
    const u16* __restrict__ A, const u16* __restrict__ Bt, float* __restrict__ C) {
  const int K = 2048;
  __shared__ __align__(16) char smem[49152];
  const int tid = threadIdx.x;
  const int wave = tid >> 6, lane = tid & 63;
  const int lrow = lane & 15, lkg = lane >> 4;
  const int m0 = blockIdx.x * 64;
  const int n0 = blockIdx.y * 128;
  const int wc = wave * 32;
  const int sw = lrow & 7;

  const int srow = tid >> 3;
  const int ssc = (tid & 7) ^ ((tid >> 3) & 7);
  const size_t abase = (size_t)(m0 + srow) * K + ssc * 8;
  const size_t bbase = (size_t)(n0 + srow) * K + ssc * 8;

  const f32x4 fzero = {0.f, 0.f, 0.f, 0.f};
  f32x4 acc[4][2];
#pragma unroll
  for (int mi = 0; mi < 4; ++mi) { acc[mi][0] = fzero; acc[mi][1] = fzero; }

#pragma unroll
  for (int it = 0; it < 2; ++it)
    stage16(A + abase + (size_t)it * 32 * K, smem + (tid + it * 256) * 16);
#pragma unroll
  for (int it = 0; it < 4; ++it)
    stage16(Bt + bbase + (size_t)it * 32 * K, smem + 16384 + (tid + it * 256) * 16);

  for (int k0 = 0, ki = 0; k0 < K; k0 += 64, ++ki) {
    const int cur = ki & 1;
    const char* Asb = smem + cur * 8192;
    const char* Bsb = smem + 16384 + cur * 16384;
    if (k0 + 64 < K) {
      char* Asn = smem + (cur ^ 1) * 8192;
      char* Bsn = smem + 16384 + (cur ^ 1) * 16384;
#pragma unroll
      for (int it = 0; it < 2; ++it)
        stage16(A + abase + (size_t)it * 32 * K + k0 + 64, Asn + (tid + it * 256) * 16);
#pragma unroll
      for (int it = 0; it < 4; ++it)
        stage16(Bt + bbase + (size_t)it * 32 * K + k0 + 64, Bsn + (tid + it * 256) * 16);
      asm volatile("s_waitcnt vmcnt(6)\n\ts_barrier" ::: "memory");
    } else {
      asm volatile("s_waitcnt vmcnt(0)\n\ts_barrier" ::: "memory");
    }
#pragma unroll
    for (int kk = 0; kk < 2; ++kk) {
      const int cof = ((kk * 4 + lkg) ^ sw) << 4;
      bf16x8 af[4], bfr[2];
#pragma unroll
      for (int mi = 0; mi < 4; ++mi)
        af[mi] = *(const bf16x8*)(Asb + (mi * 16 + lrow) * 128 + cof);
#pragma unroll
      for (int ni = 0; ni < 2; ++ni)
        bfr[ni] = *(const bf16x8*)(Bsb + (wc + ni * 16 + lrow) * 128 + cof);
#pragma unroll
      for (int mi = 0; mi < 4; ++mi)
#pragma unroll
        for (int ni = 0; ni < 2; ++ni)
          acc[mi][ni] = mfma16(af[mi], bfr[ni], acc[mi][ni]);
    }
    asm volatile("s_barrier" ::: "memory");
  }
#pragma unroll
  for (int mi = 0; mi < 4; ++mi)
#pragma unroll
    for (int ni = 0; ni < 2; ++ni) {
      int d = wc + ni * 16 + lrow;
      int mb = mi * 16 + lkg * 4;
#pragma unroll
      for (int r = 0; r < 4; ++r)
        C[(size_t)(m0 + mb + r) * 2048 + n0 + d] = acc[mi][ni][r];
    }
}

// flash attention, causal, GQA.  S^T formulation.  R6: HYBRID split --
// qb >= 16 rows split into two KV halves (partial O + ml, merged later);
// qb < 16 rows run unsplit and write normalized bf16 directly to Y (no
// partial traffic, no merge).  Grid (16, 48) = 768 blocks, work 1..16
// tiles, heavy-first; 2 blk/CU resident + backfill (proven R4 mechanism).
__global__ __launch_bounds__(256, 2) void yuna_flash_attn(
    const u16* __restrict__ Q,   // [16][2048][128] pre-scaled
    const u16* __restrict__ Kb,  // [4][2048][128]
    const u16* __restrict__ Vt,  // [4][128][2048]
    float* __restrict__ OpA,     // [16][2048][128] partial O, half A
    float* __restrict__ OpB,     // [16][2048][128] partial O, half B
    float* __restrict__ ml,      // [2][16][2048] float2 (m, l)
    u16* __restrict__ Y) {       // [2048][2048] direct out for unsplit rows
  __shared__ __align__(16) u16 Ks[2][64 * 128];
  __shared__ __align__(16) u16 Vs[2][128 * 64];
  __shared__ __align__(16) u16 Ps[64 * 64];
  const int h = blockIdx.x;
  const int yb = blockIdx.y;           // 0..47
  int qb, kb0, kb1, half;
  if (yb < 32) {                        // split rows: qb 31..16, two halves
    qb = 31 - (yb >> 1);
    half = yb & 1;
    int ca = (qb + 2) >> 1;
    kb0 = half ? ca : 0;
    kb1 = half ? (qb + 1) : ca;
  } else {                              // unsplit rows: qb 15..0
    qb = 47 - yb;
    half = 0;
    kb0 = 0;
    kb1 = qb + 1;
  }
  const bool split = (yb < 32);
  const int kvh = h >> 2;
  const int tid = threadIdx.x, wave = tid >> 6, lane = tid & 63;
  const int lrow = lane & 15, lkg = lane >> 4;
  const int m = wave * 16 + lrow;
  const int sw = lrow & 7;
  const int qglob = qb * 64 + m;

  const int krow = tid >> 4;
  const int ksc = (tid & 15) ^ ((tid >> 4) & 7);
  const size_t kbase0 = ((size_t)(kvh * 2048 + krow) << 7) + ksc * 8;
  const int vrow = tid >> 3;
  const int vsc = (tid & 7) ^ ((tid >> 3) & 7);
  const size_t vbase0 = (size_t)(kvh * 128 + vrow) * 2048 + vsc * 8;

  bf16x8 qf[4];
#pragma unroll
  for (int kk = 0; kk < 4; ++kk)
    qf[kk] = *(const bf16x8*)(Q + (((size_t)h * 2048 + qglob) << 7) + kk * 32 + lkg * 8);

  const f32x4 fzero = {0.f, 0.f, 0.f, 0.f};
  f32x4 o[8];
#pragma unroll
  for (int dt = 0; dt < 8; ++dt) o[dt] = fzero;
  float m_i = -1e30f, l_i = 0.f;   // l_i: per-LANE partial (reduced in epilogue)

  {
    // prologue: stage tile kb0
#pragma unroll
    for (int it = 0; it < 4; ++it)
      stage16(Kb + kbase0 + ((size_t)(kb0 * 64 + it * 16) << 7), (char*)Ks[0] + (tid + it * 256) * 16);
#pragma unroll
    for (int it = 0; it < 4; ++it)
      stage16(Vt + vbase0 + (size_t)it * 32 * 2048 + kb0 * 64, (char*)Vs[0] + (tid + it * 256) * 16);

    for (int kb = kb0; kb < kb1; ++kb) {
      const int cur = (kb - kb0) & 1;
      const char* Ksb = (const char*)Ks[cur];
      const char* Vsb = (const char*)Vs[cur];
      if (kb + 1 < kb1) {
        char* Ksn = (char*)Ks[cur ^ 1];
        char* Vsn = (char*)Vs[cur ^ 1];
#pragma unroll
        for (int it = 0; it < 4; ++it)
          stage16(Kb + kbase0 + ((size_t)((kb + 1) * 64 + it * 16) << 7), Ksn + (tid + it * 256) * 16);
#pragma unroll
        for (int it = 0; it < 4; ++it)
          stage16(Vt + vbase0 + (size_t)it * 32 * 2048 + (kb + 1) * 64, Vsn + (tid + it * 256) * 16);
        asm volatile("s_waitcnt vmcnt(8)\n\ts_barrier" ::: "memory");
      } else {
        asm volatile("s_waitcnt vmcnt(0)\n\ts_barrier" ::: "memory");
      }

      f32x4 s[4];
#pragma unroll
      for (int nt = 0; nt < 4; ++nt) s[nt] = fzero;
      __builtin_amdgcn_s_setprio(1);
#pragma unroll
      for (int kk = 0; kk < 4; ++kk) {
        const int cof = ((kk * 4 + lkg) ^ sw) << 4;
        bf16x8 kf[4];
#pragma unroll
        for (int nt = 0; nt < 4; ++nt)
          kf[nt] = *(const bf16x8*)(Ksb + (nt * 16 + lrow) * 256 + cof);
#pragma unroll
        for (int nt = 0; nt < 4; ++nt)
          s[nt] = mfma16(kf[nt], qf[kk], s[nt]);
      }
      __builtin_amdgcn_s_setprio(0);
      if (kb == qb) {
        const int kbase = kb * 64 + lkg * 4;
#pragma unroll
        for (int nt = 0; nt < 4; ++nt)
#pragma unroll
          for (int r = 0; r < 4; ++r)
            if (kbase + nt * 16 + r > qglob) s[nt][r] = -1e30f;
      }

      float mx = -1e30f;
#pragma unroll
      for (int nt = 0; nt < 4; ++nt)
#pragma unroll
        for (int r = 0; r < 4; ++r) mx = fmaxf(mx, s[nt][r]);
      mx = fmaxf(mx, __shfl_xor(mx, 16));
      mx = fmaxf(mx, __shfl_xor(mx, 32));
      // T13 defer-max: rescale only when some row's max grew by > 8 (log2 dom.)
      if (__any(mx > m_i + 8.0f)) {
        float mnew = fmaxf(m_i, mx);
        float alpha = fexp2(m_i - mnew);
        m_i = mnew;
        l_i *= alpha;
#pragma unroll
        for (int dt = 0; dt < 8; ++dt) o[dt] *= alpha;
      }
      float ps = 0.f;
      const int hh = lkg & 1;
#pragma unroll
      for (int nt = 0; nt < 4; ++nt) {
        float p0 = fexp2(s[nt][0] - m_i);
        float p1 = fexp2(s[nt][1] - m_i);
        float p2 = fexp2(s[nt][2] - m_i);
        float p3 = fexp2(s[nt][3] - m_i);
        ps += (p0 + p1) + (p2 + p3);
        u32x2 pk2;
        pk2.x = pack_bf2(p0, p1);
        pk2.y = pack_bf2(p2, p3);
        int cc = 2 * nt + (lkg >> 1);
        *(u32x2*)((char*)Ps + m * 128 + ((cc ^ (m & 7)) << 4) + hh * 8) = pk2;
      }
      l_i += ps;   // per-lane partial; cross-lane reduce deferred to epilogue

      __builtin_amdgcn_s_setprio(1);
#pragma unroll
      for (int kk = 0; kk < 2; ++kk) {
        const int cof = ((kk * 4 + lkg) ^ sw) << 4;
        bf16x8 pf = *(const bf16x8*)((char*)Ps + m * 128 + cof);
        bf16x8 vf[8];
#pragma unroll
        for (int dt = 0; dt < 8; ++dt)
          vf[dt] = *(const bf16x8*)(Vsb + (dt * 16 + lrow) * 128 + cof);
#pragma unroll
        for (int dt = 0; dt < 8; ++dt)
          o[dt] = mfma16(vf[dt], pf, o[dt]);
      }
      __builtin_amdgcn_s_setprio(0);
      asm volatile("s_barrier" ::: "memory");
    }
  }

  // ---- epilogue ----
  l_i += __shfl_xor(l_i, 16);
  l_i += __shfl_xor(l_i, 32);
  if (split) {
    // write partial O (unnormalized, fp32) + per-row (m, l)
    size_t row = (size_t)h * 2048 + qglob;
    if (lkg == 0)
      *(float2*)(ml + ((size_t)(half << 15) + row) * 2) = float2{m_i, l_i};
    float* orow = (half ? OpB : OpA) + row * 128 + lkg * 4;
#pragma unroll
    for (int dt = 0; dt < 8; ++dt)
      *(f32x4*)(orow + dt * 16) = o[dt];
  } else {
    // normalize + pack bf16 + LDS transpose + coalesced write to Y
    __syncthreads();
    {
      float inv = 1.f / l_i;
      const int hh = lkg & 1;
#pragma unroll
      for (int dt = 0; dt < 8; ++dt) {
        u32x2 w2;
        w2.x = pack_bf2(o[dt][0] * inv, o[dt][1] * inv);
        w2.y = pack_bf2(o[dt][2] * inv, o[dt][3] * inv);
        int cc = 2 * dt + (lkg >> 1);
        *(u32x2*)((char*)Ks + m * 256 + ((cc ^ (m & 7)) << 4) + hh * 8) = w2;
      }
    }
    __syncthreads();
#pragma unroll
    for (int it = 0; it < 4; ++it) {
      int c = tid + it * 256;
      int row = c >> 4, cc = c & 15;
      f32x4 v = *(const f32x4*)((const char*)Ks + row * 256 + ((cc ^ (row & 7)) << 4));
      *(f32x4*)(Y + (size_t)(qb * 64 + row) * 2048 + h * 128 + cc * 8) = v;
    }
  }
}

// merge the two KV-split halves (t >= 1024 rows only):
// O = (OA*wA + OB*wB) / (lA*wA + lB*wB)
__global__ void yuna_merge(const float* __restrict__ OpA, const float* __restrict__ OpB,
                           const float* __restrict__ ml, u16* __restrict__ Y) {
  int idx = blockIdx.x * 256 + threadIdx.x;  // 16h x 1024t x 32(d/4) = 524288
  int d4 = idx & 31;
  int t = 1024 + ((idx >> 5) & 1023);
  int h = idx >> 15;
  size_t row = (size_t)h * 2048 + t;
  float2 a2 = *(const float2*)(ml + row * 2);
  float2 b2 = *(const float2*)(ml + (32768 + row) * 2);
  float M = fmaxf(a2.x, b2.x);
  float wA = fexp2(a2.x - M), wB = fexp2(b2.x - M);
  float inv = 1.f / (a2.y * wA + b2.y * wB);
  wA *= inv; wB *= inv;
  f32x4 a = ((const f32x4*)OpA)[row * 32 + d4];
  f32x4 b = ((const f32x4*)OpB)[row * 32 + d4];
  u16x4 w;
  w.x = f2bf(a[0] * wA + b[0] * wB);
  w.y = f2bf(a[1] * wA + b[1] * wB);
  w.z = f2bf(a[2] * wA + b[2] * wB);
  w.w = f2bf(a[3] * wA + b[3] * wB);
  *(u16x4*)(Y + (size_t)t * 2048 + h * 128 + d4 * 4) = w;
}

// ---------- launch ----------

extern "C" void kernel_launch(void* const* d_in, const int* in_sizes, int n_in,
                              void* d_out, int out_size, void* d_ws, size_t ws_size,
                              hipStream_t stream) {
  const float* x = (const float*)d_in[0];
  const float* cosp = (const float*)d_in[1];
  const float* sinp = (const float*)d_in[2];
  const float* Wq = (const float*)d_in[3];
  const float* bq = (const float*)d_in[4];
  const float* Wk = (const float*)d_in[5];
  const float* bk = (const float*)d_in[6];
  const float* Wv = (const float*)d_in[7];
  const float* bv = (const float*)d_in[8];
  const float* Wo = (const float*)d_in[9];
  float* out = (float*)d_out;
  float* out_k = out + 4194304;
  float* out_v = out + 5242880;

  char* ws = (char*)d_ws;
  u16* xb   = (u16*)(ws + 0);          //  8 MB  x  bf16            (dead after gemm_qkv)
  u16* Wb   = (u16*)(ws + 8388608);    // 12 MB  fused W^T bf16     (dead after gemm_qkv)
  u16* Wob  = (u16*)(ws + 20971520);   //  8 MB  Wo^T bf16          (live until gemm_out)
  float* csel = (float*)(ws + 29360128); // 1 MB rope cos table
  float* ssel = (float*)(ws + 30408704); // 1 MB rope sin table
  u16* qbuf = (u16*)(ws + 54525952);   //  8 MB  q bf16 [16][2048][128]
  u16* kbuf = (u16*)(ws + 62914560);   //  2 MB  k bf16 [4][2048][128]
  u16* vtb  = (u16*)(ws + 65011712);   //  2 MB  v^T bf16 [4][128][2048]
  u16* yat  = (u16*)(ws + 67108864);   //  8 MB  attn out bf16 [2048][2048]
  // flash-time scratch (overlaps regions dead by then):
  float* opA = (float*)(ws + 0);          // 16.78 MB (over xb+Wb head)
  float* mlb = (float*)(ws + 17825792);   //  1 MB  [2][16][2048] float2 (in Wb tail)
  float* opB = (float*)(ws + 31457280);   // 16.78 MB (gap before qbuf)

  yuna_prep<<<8448, 256, 0, stream>>>(x, xb, cosp, sinp, csel, ssel,
                                      Wq, Wk, Wv, Wo, Wb, Wob);
  yuna_gemm_qkv<<<dim3(32, 24), 256, 0, stream>>>(xb, Wb, bq, bk, bv, csel, ssel,
                                                  qbuf, kbuf, vtb, out_k, out_v);
  yuna_flash_attn<<<dim3(16, 48), 256, 0, stream>>>(qbuf, kbuf, vtb, opA, opB, mlb, yat);
  yuna_merge<<<2048, 256, 0, stream>>>(opA, opB, mlb, yat);
  yuna_gemm_out<<<dim3(32, 16), 256, 0, stream>>>(yat, Wob, out);
}

// Round 7
// 216.850 us; speedup vs baseline: 1.0321x; 1.0321x over previous
//
#include <hip/hip_runtime.h>

typedef unsigned short u16;
typedef unsigned int u32;
typedef __attribute__((ext_vector_type(4))) float f32x4;
typedef __attribute__((ext_vector_type(8))) __bf16 bf16x8;
typedef __attribute__((ext_vector_type(4))) u16 u16x4;
typedef __attribute__((ext_vector_type(2))) u32 u32x2;

// ---------- helpers ----------

__device__ __forceinline__ u16 f2bf(float f) {
  union { float f; unsigned u; } v; v.f = f;
  unsigned r = v.u + 0x7fffu + ((v.u >> 16) & 1u);
  return (u16)(r >> 16);
}

// pack two floats to bf16x2 (round-half-up) via v_perm
__device__ __forceinline__ u32 pack_bf2(float a, float b) {
  union { float f; unsigned u; } x, y;
  x.f = a; y.f = b;
#if __has_builtin(__builtin_amdgcn_perm)
  return __builtin_amdgcn_perm(y.u + 0x8000u, x.u + 0x8000u, 0x07060302u);
#else
  return (u32)((x.u + 0x8000u) >> 16) | ((y.u + 0x8000u) & 0xffff0000u);
#endif
}

__device__ __forceinline__ void stage16(const void* g, void* l) {
#if __has_builtin(__builtin_amdgcn_global_load_lds)
  __builtin_amdgcn_global_load_lds((const __attribute__((address_space(1))) void*)g,
                                   (__attribute__((address_space(3))) void*)l, 16, 0, 0);
#else
  *(f32x4*)l = *(const f32x4*)g;
#endif
}

__device__ __forceinline__ f32x4 mfma16(bf16x8 a, bf16x8 b, f32x4 c) {
  return __builtin_amdgcn_mfma_f32_16x16x32_bf16(a, b, c, 0, 0, 0);
}

__device__ __forceinline__ float fexp2(float x) {
#if __has_builtin(__builtin_amdgcn_exp2f)
  return __builtin_amdgcn_exp2f(x);
#else
  return exp2f(x);
#endif
}

// rope channel select: sections [16,24,24,16,24,24] -> channels 0,1,2,0,1,2
__device__ __forceinline__ int rope_ch(int d) {
  int dd = (d < 64) ? d : d - 64;
  return (dd < 16) ? 0 : (dd < 40 ? 1 : 2);
}

// ---------- kernels ----------

// Merged prep: one launch instead of two (independent, both memory-bound).
// bid < 4096:            weight transpose (mat = bid>>10)
// 4096 <= bid < 8192:    x fp32 -> bf16
// 8192 <= bid < 8448:    rope channel-select tables
__global__ void yuna_prep(const float* __restrict__ x, u16* __restrict__ xb,
                          const float* __restrict__ cosp, const float* __restrict__ sinp,
                          float* __restrict__ csel, float* __restrict__ ssel,
                          const float* __restrict__ Wq, const float* __restrict__ Wk,
                          const float* __restrict__ Wv, const float* __restrict__ Wo,
                          u16* __restrict__ Wb, u16* __restrict__ Wob) {
  __shared__ float tile[64][65];
  const int bid = blockIdx.x;
  if (bid < 4096) {
    // ---- fused weight transpose: out[n][k] = bf16(W[k][n]) ----
    const int mat = bid >> 10;
    const int rem = bid & 1023;
    const float* W;
    u16* out;
    int N;
    if (mat == 0)      { W = Wq; out = Wb;                          N = 2048; }
    else if (mat == 1) { W = Wk; out = Wb + (size_t)2048 * 2048;    N = 512; }
    else if (mat == 2) { W = Wv; out = Wb + (size_t)2560 * 2048;    N = 512; }
    else               { W = Wo; out = Wob;                         N = 2048; }
    int k0 = (rem & 31) << 6, n0 = (rem >> 5) << 6;
    if (n0 >= N) return;
    int tx = threadIdx.x & 63, ty = threadIdx.x >> 6;
#pragma unroll
    for (int j = 0; j < 64; j += 4)
      tile[ty + j][tx] = W[(size_t)(k0 + ty + j) * N + n0 + tx];
    __syncthreads();
#pragma unroll
    for (int j = 0; j < 64; j += 4)
      out[(size_t)(n0 + ty + j) * 2048 + k0 + tx] = f2bf(tile[tx][ty + j]);
  } else if (bid < 8192) {
    // ---- x fp32 -> bf16 ----
    int i = (bid - 4096) * 256 + threadIdx.x;
    f32x4 v = ((const f32x4*)x)[i];
    u16x4 o;
    o.x = f2bf(v.x); o.y = f2bf(v.y); o.z = f2bf(v.z); o.w = f2bf(v.w);
    ((u16x4*)xb)[i] = o;
  } else {
    // ---- rope tables csel/ssel[t][d] = cos/sin[ch(d)][t][d] ----
    int i = (bid - 8192) * 256 + threadIdx.x;  // 0..65535, 4 elems each
    int i4 = i * 4;
    int t = i4 >> 7, d = i4 & 127;
    f32x4 c, s;
#pragma unroll
    for (int j = 0; j < 4; ++j) {
      int ch = rope_ch(d + j);
      c[j] = cosp[(size_t)ch * 262144 + (size_t)t * 128 + d + j];
      s[j] = sinp[(size_t)ch * 262144 + (size_t)t * 128 + d + j];
    }
    ((f32x4*)csel)[i] = c;
    ((f32x4*)ssel)[i] = s;
  }
}

// Fused QKV GEMM + bias + rope + scatter.  64x128 tile, grid (32,24) = 768
// blocks = exactly 3/CU (R5's 128x128 at 1.5 blk/CU was slower -- balance
// beats per-step MFMA:read ratio at these shapes).
// A [2048][2048] bf16 (x), Bt [3072][2048] bf16 (W^T fused).
// Column mapping: wave w owns cols {w*16..+15} u {w*16+64..+79}: rope pair
// in-lane.  by<16 -> Q head, 16..19 -> K head, 20..23 -> V head.
__global__ __launch_bounds__(256, 3) void yuna_gemm_qkv(
    const u16* __restrict__ A, const u16* __restrict__ Bt,
    const float* __restrict__ bq, const float* __restrict__ bk, const float* __restrict__ bv,
    const float* __restrict__ csel, const float* __restrict__ ssel,
    u16* __restrict__ qb, u16* __restrict__ kb, u16* __restrict__ vtb,
    float* __restrict__ pk, float* __restrict__ pv) {
  const int K = 2048;
  __shared__ __align__(16) char smem[49152];  // As[2]:16K @0, Bs[2]:32K @16K
  const int tid = threadIdx.x;
  const int wave = tid >> 6, lane = tid & 63;
  const int lrow = lane & 15, lkg = lane >> 4;
  const int m0 = blockIdx.x * 64;
  const int by = blockIdx.y;
  const int n0 = by * 128;
  const int sw = lrow & 7;

  const int srow = tid >> 3;
  const int ssc = (tid & 7) ^ ((tid >> 3) & 7);
  const size_t abase = (size_t)(m0 + srow) * K + ssc * 8;
  const size_t bbase = (size_t)(n0 + srow) * K + ssc * 8;

  const f32x4 fzero = {0.f, 0.f, 0.f, 0.f};
  f32x4 acc[4][2];
#pragma unroll
  for (int mi = 0; mi < 4; ++mi) { acc[mi][0] = fzero; acc[mi][1] = fzero; }

  // prologue: stage k-tile 0 into buffer 0 (6 loads/thread)
#pragma unroll
  for (int it = 0; it < 2; ++it)
    stage16(A + abase + (size_t)it * 32 * K, smem + (tid + it * 256) * 16);
#pragma unroll
  for (int it = 0; it < 4; ++it)
    stage16(Bt + bbase + (size_t)it * 32 * K, smem + 16384 + (tid + it * 256) * 16);

  for (int k0 = 0, ki = 0; k0 < K; k0 += 64, ++ki) {
    const int cur = ki & 1;
    const char* Asb = smem + cur * 8192;
    const char* Bsb = smem + 16384 + cur * 16384;
    if (k0 + 64 < K) {
      char* Asn = smem + (cur ^ 1) * 8192;
      char* Bsn = smem + 16384 + (cur ^ 1) * 16384;
#pragma unroll
      for (int it = 0; it < 2; ++it)
        stage16(A + abase + (size_t)it * 32 * K + k0 + 64, Asn + (tid + it * 256) * 16);
#pragma unroll
      for (int it = 0; it < 4; ++it)
        stage16(Bt + bbase + (size_t)it * 32 * K + k0 + 64, Bsn + (tid + it * 256) * 16);
      asm volatile("s_waitcnt vmcnt(6)\n\ts_barrier" ::: "memory");
    } else {
      asm volatile("s_waitcnt vmcnt(0)\n\ts_barrier" ::: "memory");
    }
#pragma unroll
    for (int kk = 0; kk < 2; ++kk) {
      const int cof = ((kk * 4 + lkg) ^ sw) << 4;
      bf16x8 af[4], bfr[2];
#pragma unroll
      for (int mi = 0; mi < 4; ++mi)
        af[mi] = *(const bf16x8*)(Asb + (mi * 16 + lrow) * 128 + cof);
#pragma unroll
      for (int ni = 0; ni < 2; ++ni)
        bfr[ni] = *(const bf16x8*)(Bsb + (wave * 16 + ni * 64 + lrow) * 128 + cof);
#pragma unroll
      for (int mi = 0; mi < 4; ++mi)
#pragma unroll
        for (int ni = 0; ni < 2; ++ni)
          acc[mi][ni] = mfma16(af[mi], bfr[ni], acc[mi][ni]);
    }
    asm volatile("s_barrier" ::: "memory");
  }

  // ---- epilogue ----  acc[mi][ni][r]: t = m0+mi*16+lkg*4+r, d = wave*16+ni*64+lrow
  if (by >= 20) {
    // V: bias, write pv fp32 [kvh][t][d] + vtb bf16 [kvh][d][t] (4 t's packed)
    const int kvh = by - 20;
#pragma unroll
    for (int mi = 0; mi < 4; ++mi)
#pragma unroll
      for (int ni = 0; ni < 2; ++ni) {
        int d = wave * 16 + ni * 64 + lrow;
        float bb = bv[kvh * 128 + d];
        int mb = mi * 16 + lkg * 4;
        float v0 = acc[mi][ni][0] + bb, v1 = acc[mi][ni][1] + bb;
        float v2 = acc[mi][ni][2] + bb, v3 = acc[mi][ni][3] + bb;
        size_t pb = ((size_t)(kvh * 2048 + m0 + mb)) * 128 + d;
        pv[pb] = v0; pv[pb + 128] = v1; pv[pb + 256] = v2; pv[pb + 384] = v3;
        u16x4 w;
        w.x = f2bf(v0); w.y = f2bf(v1); w.z = f2bf(v2); w.w = f2bf(v3);
        *(u16x4*)(vtb + ((size_t)(kvh * 128 + d)) * 2048 + m0 + mb) = w;
      }
  } else {
    // Q/K: rope entirely in registers (acc[mi][0] = chan d, acc[mi][1] = chan d+64)
    const float QSCALE = 1.4426950408889634f * 0.08838834764831845f;
    const bool isQ = (by < 16);
    const int h = isQ ? by : (by - 16);
    const float* bias = isQ ? bq : bk;
    const int dlo = wave * 16 + lrow;
    const float blo = bias[h * 128 + dlo];
    const float bhi = bias[h * 128 + dlo + 64];
#pragma unroll
    for (int mi = 0; mi < 4; ++mi) {
      const int tb = m0 + mi * 16 + lkg * 4;
#pragma unroll
      for (int r = 0; r < 4; ++r) {
        const int t = tb + r;
        float a = acc[mi][0][r] + blo;
        float b = acc[mi][1][r] + bhi;
        size_t cb = (size_t)t * 128 + dlo;
        float cl = csel[cb], sl = ssel[cb];
        float ch = csel[cb + 64], sh = ssel[cb + 64];
        float lo = a * cl - b * sl;
        float hi = b * ch + a * sh;
        size_t o = (((size_t)(h * 2048 + t)) << 7) + dlo;
        if (isQ) {
          qb[o] = f2bf(lo * QSCALE);
          qb[o + 64] = f2bf(hi * QSCALE);
        } else {
          kb[o] = f2bf(lo);
          kb[o + 64] = f2bf(hi);
          pk[o] = lo; pk[o + 64] = hi;
        }
      }
    }
  }
}

// Output GEMM: C[2048][2048] fp32 = A(yat) @ Wob^T.  64x128 tile,
// grid (32,16) = 512 = exactly 2/CU.
__global__ __launch_bounds__(256, 3) void yuna_gemm_out(
    const u16* __restrict__ A, const u16* __restrict__ Bt, float* __restrict__ C) {
  const int K = 2048;
  __shared__ __align__(16) char smem[49152];
  const int tid = threadIdx.x;
  const int wave = tid >> 6, lane = tid & 63;
  const int lrow = lane & 15, lkg = lane >> 4;
  const int m0 = blockIdx.x * 64;
  const int n0 = blockIdx.y * 128;
  const int wc = wave * 32;
  const int sw = lrow & 7;

  const int srow = tid >> 3;
  const int ssc = (tid & 7) ^ ((tid >> 3) & 7);
  const size_t abase = (size_t)(m0 + srow) * K + ssc * 8;
  const size_t bbase = (size_t)(n0 + srow) * K + ssc * 8;

  const f32x4 fzero = {0.f, 0.f, 0.f, 0.f};
  f32x4 acc[4][2];
#pragma unroll
  for (int mi = 0; mi < 4; ++mi) { acc[mi][0] = fzero; acc[mi][1] = fzero; }

#pragma unroll
  for (int it = 0; it < 2; ++it)
    stage16(A + abase + (size_t)it * 32 * K, smem + (tid + it * 256) * 16);
#pragma unroll
  for (int it = 0; it < 4; ++it)
    stage16(Bt + bbase + (size_t)it * 32 * K, smem + 16384 + (tid + it * 256) * 16);

  for (int k0 = 0, ki = 0; k0 < K; k0 += 64, ++ki) {
    const int cur = ki & 1;
    const char* Asb = smem + cur * 8192;
    const char* Bsb = smem + 16384 + cur * 16384;
    if (k0 + 64 < K) {
      char* Asn = smem + (cur ^ 1) * 8192;
      char* Bsn = smem + 16384 + (cur ^ 1) * 16384;
#pragma unroll
      for (int it = 0; it < 2; ++it)
        stage16(A + abase + (size_t)it * 32 * K + k0 + 64, Asn + (tid + it * 256) * 16);
#pragma unroll
      for (int it = 0; it < 4; ++it)
        stage16(Bt + bbase + (size_t)it * 32 * K + k0 + 64, Bsn + (tid + it * 256) * 16);
      asm volatile("s_waitcnt vmcnt(6)\n\ts_barrier" ::: "memory");
    } else {
      asm volatile("s_waitcnt vmcnt(0)\n\ts_barrier" ::: "memory");
    }
#pragma unroll
    for (int kk = 0; kk < 2; ++kk) {
      const int cof = ((kk * 4 + lkg) ^ sw) << 4;
      bf16x8 af[4], bfr[2];
#pragma unroll
      for (int mi = 0; mi < 4; ++mi)
        af[mi] = *(const bf16x8*)(Asb + (mi * 16 + lrow) * 128 + cof);
#pragma unroll
      for (int ni = 0; ni < 2; ++ni)
        bfr[ni] = *(const bf16x8*)(Bsb + (wc + ni * 16 + lrow) * 128 + cof);
#pragma unroll
      for (int mi = 0; mi < 4; ++mi)
#pragma unroll
        for (int ni = 0; ni < 2; ++ni)
          acc[mi][ni] = mfma16(af[mi], bfr[ni], acc[mi][ni]);
    }
    asm volatile("s_barrier" ::: "memory");
  }
#pragma unroll
  for (int mi = 0; mi < 4; ++mi)
#pragma unroll
    for (int ni = 0; ni < 2; ++ni) {
      int d = wc + ni * 16 + lrow;
      int mb = mi * 16 + lkg * 4;
#pragma unroll
      for (int r = 0; r < 4; ++r)
        C[(size_t)(m0 + mb + r) * 2048 + n0 + d] = acc[mi][ni][r];
    }
}

// flash attention, causal, GQA.  S^T formulation.  FULL KV-SPLIT (R4 form,
// the session-best scheduling: 1024 near-equal blocks, heavy-first, HW
// backfill; R6's hybrid had heavy blocks in the launch tail -> regressed).
// R7 delta: softmax max-reduce fast path -- if no lane's LOCAL partial max
// exceeds m_i + 8, the row max doesn't either, so both cross-lane shfls AND
// the rescale are skipped (common path after the first tiles is shfl-free).
// Same defer-max numerics (P bounded by 2^8, fp32 accum).
__global__ __launch_bounds__(256, 2) void yuna_flash_attn(
    const u16* __restrict__ Q,   // [16][2048][128] pre-scaled
    const u16* __restrict__ Kb,  // [4][2048][128]
    const u16* __restrict__ Vt,  // [4][128][2048]
    float* __restrict__ OpA,     // [16][2048][128] partial O, half A
    float* __restrict__ OpB,     // [16][2048][128] partial O, half B
    float* __restrict__ ml) {    // [2][16][2048] float2 (m, l)
  __shared__ __align__(16) u16 Ks[2][64 * 128];
  __shared__ __align__(16) u16 Vs[2][128 * 64];
  __shared__ __align__(16) u16 Ps[64 * 64];
  const int h = blockIdx.x;
  const int yb = blockIdx.y;           // 0..63, work-descending
  const int qb = 31 - (yb >> 1);
  const int half = yb & 1;
  const int ca = (qb + 2) >> 1;        // split point (ceil half to A)
  const int kb0 = half ? ca : 0;
  const int kb1 = half ? (qb + 1) : ca;
  const int kvh = h >> 2;
  const int tid = threadIdx.x, wave = tid >> 6, lane = tid & 63;
  const int lrow = lane & 15, lkg = lane >> 4;
  const int m = wave * 16 + lrow;
  const int sw = lrow & 7;
  const int qglob = qb * 64 + m;

  const int krow = tid >> 4;
  const int ksc = (tid & 15) ^ ((tid >> 4) & 7);
  const size_t kbase0 = ((size_t)(kvh * 2048 + krow) << 7) + ksc * 8;
  const int vrow = tid >> 3;
  const int vsc = (tid & 7) ^ ((tid >> 3) & 7);
  const size_t vbase0 = (size_t)(kvh * 128 + vrow) * 2048 + vsc * 8;

  bf16x8 qf[4];
#pragma unroll
  for (int kk = 0; kk < 4; ++kk)
    qf[kk] = *(const bf16x8*)(Q + (((size_t)h * 2048 + qglob) << 7) + kk * 32 + lkg * 8);

  const f32x4 fzero = {0.f, 0.f, 0.f, 0.f};
  f32x4 o[8];
#pragma unroll
  for (int dt = 0; dt < 8; ++dt) o[dt] = fzero;
  float m_i = -1e30f, l_i = 0.f;   // l_i: per-LANE partial (reduced in epilogue)

  if (kb0 < kb1) {
    // prologue: stage tile kb0
#pragma unroll
    for (int it = 0; it < 4; ++it)
      stage16(Kb + kbase0 + ((size_t)(kb0 * 64 + it * 16) << 7), (char*)Ks[0] + (tid + it * 256) * 16);
#pragma unroll
    for (int it = 0; it < 4; ++it)
      stage16(Vt + vbase0 + (size_t)it * 32 * 2048 + kb0 * 64, (char*)Vs[0] + (tid + it * 256) * 16);

    for (int kb = kb0; kb < kb1; ++kb) {
      const int cur = (kb - kb0) & 1;
      const char* Ksb = (const char*)Ks[cur];
      const char* Vsb = (const char*)Vs[cur];
      if (kb + 1 < kb1) {
        char* Ksn = (char*)Ks[cur ^ 1];
        char* Vsn = (char*)Vs[cur ^ 1];
#pragma unroll
        for (int it = 0; it < 4; ++it)
          stage16(Kb + kbase0 + ((size_t)((kb + 1) * 64 + it * 16) << 7), Ksn + (tid + it * 256) * 16);
#pragma unroll
        for (int it = 0; it < 4; ++it)
          stage16(Vt + vbase0 + (size_t)it * 32 * 2048 + (kb + 1) * 64, Vsn + (tid + it * 256) * 16);
        asm volatile("s_waitcnt vmcnt(8)\n\ts_barrier" ::: "memory");
      } else {
        asm volatile("s_waitcnt vmcnt(0)\n\ts_barrier" ::: "memory");
      }

      f32x4 s[4];
#pragma unroll
      for (int nt = 0; nt < 4; ++nt) s[nt] = fzero;
      __builtin_amdgcn_s_setprio(1);
#pragma unroll
      for (int kk = 0; kk < 4; ++kk) {
        const int cof = ((kk * 4 + lkg) ^ sw) << 4;
        bf16x8 kf[4];
#pragma unroll
        for (int nt = 0; nt < 4; ++nt)
          kf[nt] = *(const bf16x8*)(Ksb + (nt * 16 + lrow) * 256 + cof);
#pragma unroll
        for (int nt = 0; nt < 4; ++nt)
          s[nt] = mfma16(kf[nt], qf[kk], s[nt]);
      }
      __builtin_amdgcn_s_setprio(0);
      if (kb == qb) {
        const int kbase = kb * 64 + lkg * 4;
#pragma unroll
        for (int nt = 0; nt < 4; ++nt)
#pragma unroll
          for (int r = 0; r < 4; ++r)
            if (kbase + nt * 16 + r > qglob) s[nt][r] = -1e30f;
      }

      // local (per-lane) partial max over this lane's 16 values of the row
      float mxl = -1e30f;
#pragma unroll
      for (int nt = 0; nt < 4; ++nt)
#pragma unroll
        for (int r = 0; r < 4; ++r) mxl = fmaxf(mxl, s[nt][r]);
      // fast path: if no lane's local max exceeds m_i + 8, the row max
      // doesn't either -> skip cross-lane reduce AND rescale entirely.
      if (__any(mxl > m_i + 8.0f)) {
        float mx = fmaxf(mxl, __shfl_xor(mxl, 16));
        mx = fmaxf(mx, __shfl_xor(mx, 32));
        float mnew = fmaxf(m_i, mx);
        float alpha = fexp2(m_i - mnew);
        m_i = mnew;
        l_i *= alpha;
#pragma unroll
        for (int dt = 0; dt < 8; ++dt) o[dt] *= alpha;
      }
      float ps = 0.f;
      const int hh = lkg & 1;
#pragma unroll
      for (int nt = 0; nt < 4; ++nt) {
        float p0 = fexp2(s[nt][0] - m_i);
        float p1 = fexp2(s[nt][1] - m_i);
        float p2 = fexp2(s[nt][2] - m_i);
        float p3 = fexp2(s[nt][3] - m_i);
        ps += (p0 + p1) + (p2 + p3);
        u32x2 pk2;
        pk2.x = pack_bf2(p0, p1);
        pk2.y = pack_bf2(p2, p3);
        int cc = 2 * nt + (lkg >> 1);
        *(u32x2*)((char*)Ps + m * 128 + ((cc ^ (m & 7)) << 4) + hh * 8) = pk2;
      }
      l_i += ps;   // per-lane partial; cross-lane reduce deferred to epilogue

      __builtin_amdgcn_s_setprio(1);
#pragma unroll
      for (int kk = 0; kk < 2; ++kk) {
        const int cof = ((kk * 4 + lkg) ^ sw) << 4;
        bf16x8 pf = *(const bf16x8*)((char*)Ps + m * 128 + cof);
        bf16x8 vf[8];
#pragma unroll
        for (int dt = 0; dt < 8; ++dt)
          vf[dt] = *(const bf16x8*)(Vsb + (dt * 16 + lrow) * 128 + cof);
#pragma unroll
        for (int dt = 0; dt < 8; ++dt)
          o[dt] = mfma16(vf[dt], pf, o[dt]);
      }
      __builtin_amdgcn_s_setprio(0);
      asm volatile("s_barrier" ::: "memory");
    }
  }

  // ---- epilogue: write partial O (unnormalized, fp32) + per-row (m, l) ----
  l_i += __shfl_xor(l_i, 16);
  l_i += __shfl_xor(l_i, 32);
  size_t row = (size_t)h * 2048 + qglob;
  if (lkg == 0)
    *(float2*)(ml + ((size_t)(half << 15) + row) * 2) = float2{m_i, l_i};
  float* orow = (half ? OpB : OpA) + row * 128 + lkg * 4;
#pragma unroll
  for (int dt = 0; dt < 8; ++dt)
    *(f32x4*)(orow + dt * 16) = o[dt];
}

// merge the two KV-split halves: O = (OA*wA + OB*wB) / (lA*wA + lB*wB)
__global__ void yuna_merge(const float* __restrict__ OpA, const float* __restrict__ OpB,
                           const float* __restrict__ ml, u16* __restrict__ Y) {
  int idx = blockIdx.x * 256 + threadIdx.x;  // 16h x 2048t x 32(d/4) = 1,048,576
  int d4 = idx & 31;
  int t = (idx >> 5) & 2047;
  int h = idx >> 16;
  size_t row = (size_t)h * 2048 + t;
  float2 a2 = *(const float2*)(ml + row * 2);
  float2 b2 = *(const float2*)(ml + (32768 + row) * 2);
  float M = fmaxf(a2.x, b2.x);
  float wA = fexp2(a2.x - M), wB = fexp2(b2.x - M);
  float inv = 1.f / (a2.y * wA + b2.y * wB);
  wA *= inv; wB *= inv;
  f32x4 a = ((const f32x4*)OpA)[row * 32 + d4];
  f32x4 b = ((const f32x4*)OpB)[row * 32 + d4];
  u16x4 w;
  w.x = f2bf(a[0] * wA + b[0] * wB);
  w.y = f2bf(a[1] * wA + b[1] * wB);
  w.z = f2bf(a[2] * wA + b[2] * wB);
  w.w = f2bf(a[3] * wA + b[3] * wB);
  *(u16x4*)(Y + (size_t)t * 2048 + h * 128 + d4 * 4) = w;
}

// ---------- launch ----------

extern "C" void kernel_launch(void* const* d_in, const int* in_sizes, int n_in,
                              void* d_out, int out_size, void* d_ws, size_t ws_size,
                              hipStream_t stream) {
  const float* x = (const float*)d_in[0];
  const float* cosp = (const float*)d_in[1];
  const float* sinp = (const float*)d_in[2];
  const float* Wq = (const float*)d_in[3];
  const float* bq = (const float*)d_in[4];
  const float* Wk = (const float*)d_in[5];
  const float* bk = (const float*)d_in[6];
  const float* Wv = (const float*)d_in[7];
  const float* bv = (const float*)d_in[8];
  const float* Wo = (const float*)d_in[9];
  float* out = (float*)d_out;
  float* out_k = out + 4194304;
  float* out_v = out + 5242880;

  char* ws = (char*)d_ws;
  u16* xb   = (u16*)(ws + 0);          //  8 MB  x  bf16            (dead after gemm_qkv)
  u16* Wb   = (u16*)(ws + 8388608);    // 12 MB  fused W^T bf16     (dead after gemm_qkv)
  u16* Wob  = (u16*)(ws + 20971520);   //  8 MB  Wo^T bf16          (live until gemm_out)
  float* csel = (float*)(ws + 29360128); // 1 MB rope cos table
  float* ssel = (float*)(ws + 30408704); // 1 MB rope sin table
  u16* qbuf = (u16*)(ws + 54525952);   //  8 MB  q bf16 [16][2048][128]
  u16* kbuf = (u16*)(ws + 62914560);   //  2 MB  k bf16 [4][2048][128]
  u16* vtb  = (u16*)(ws + 65011712);   //  2 MB  v^T bf16 [4][128][2048]
  u16* yat  = (u16*)(ws + 67108864);   //  8 MB  attn out bf16 [2048][2048]
  // flash-time scratch (overlaps regions dead by then):
  float* opA = (float*)(ws + 0);          // 16.78 MB (over xb+Wb head)
  float* mlb = (float*)(ws + 17825792);   //  1 MB  [2][16][2048] float2 (in Wb tail)
  float* opB = (float*)(ws + 31457280);   // 16.78 MB (gap before qbuf)

  yuna_prep<<<8448, 256, 0, stream>>>(x, xb, cosp, sinp, csel, ssel,
                                      Wq, Wk, Wv, Wo, Wb, Wob);
  yuna_gemm_qkv<<<dim3(32, 24), 256, 0, stream>>>(xb, Wb, bq, bk, bv, csel, ssel,
                                                  qbuf, kbuf, vtb, out_k, out_v);
  yuna_flash_attn<<<dim3(16, 64), 256, 0, stream>>>(qbuf, kbuf, vtb, opA, opB, mlb);
  yuna_merge<<<4096, 256, 0, stream>>>(opA, opB, mlb, yat);
  yuna_gemm_out<<<dim3(32, 16), 256, 0, stream>>>(yat, Wob, out);
}